// Round 8
// baseline (1368.211 us; speedup 1.0000x reference)
//
#include <hip/hip_runtime.h>
#include <math.h>
#include <type_traits>

// ---------------------------------------------------------------------------
// CapsNet forward, fused routing with o-SPLIT across paired blocks:
//   256 blocks = 2 per sample (half the out-caps each) -> all 256 CUs busy.
//   Cross-block dataflow: softmax denominator (64 f/iter) and layer-end v
//   (8 KB, 3x) via workspace + device-scope flag spin (partner = B ^ 128,
//   same XCD under round-robin). LDS > 80 KB forces 1 block/CU so all 256
//   blocks are co-resident (no spin deadlock); flags zeroed per launch.
// ---------------------------------------------------------------------------

__global__ void zero_flags_kernel(int* flags) { flags[threadIdx.x] = 0; }

__global__ __launch_bounds__(256) void conv_squash_kernel(
    const float* __restrict__ x,   // [128,64,8,8]
    const float* __restrict__ Wb,  // [64,64,3,3]
    const float* __restrict__ bb,  // [64]
    float* __restrict__ h)         // [128,64,64]
{
    __shared__ float xs[6400];
    __shared__ float hs[4096];
    __shared__ float scl[64];
    const int b = blockIdx.x;
    const int t = threadIdx.x;

    for (int idx = t; idx < 6400; idx += 256) xs[idx] = 0.f;
    __syncthreads();
    #pragma unroll
    for (int k = 0; k < 4; ++k) {
        int idx4 = t + k * 256;
        float4 v = *(const float4*)&x[(size_t)b * 4096 + idx4 * 4];
        int e0 = idx4 * 4;
        int c  = e0 >> 6;
        int hw = e0 & 63;
        int r = hw >> 3, cc = hw & 7;
        float* xp = &xs[c * 100 + (r + 1) * 10 + (cc + 1)];
        xp[0] = v.x; xp[1] = v.y; xp[2] = v.z; xp[3] = v.w;
    }
    __syncthreads();

    const int oc = t >> 2;
    const int hg = t & 3;
    float acc[16];
    #pragma unroll
    for (int k = 0; k < 16; ++k) acc[k] = 0.f;

    const float* wp = Wb + (size_t)oc * 64 * 9;
    for (int ic = 0; ic < 64; ++ic) {
        float w[9];
        #pragma unroll
        for (int j = 0; j < 9; ++j) w[j] = wp[ic * 9 + j];
        const float* xr = &xs[ic * 100];
        #pragma unroll
        for (int k = 0; k < 16; ++k) {
            int hw = hg * 16 + k;
            int r = hw >> 3, cc = hw & 7;
            int p0 = r * 10 + cc;
            float a = acc[k];
            a = fmaf(w[0], xr[p0],      a);
            a = fmaf(w[1], xr[p0 + 1],  a);
            a = fmaf(w[2], xr[p0 + 2],  a);
            a = fmaf(w[3], xr[p0 + 10], a);
            a = fmaf(w[4], xr[p0 + 11], a);
            a = fmaf(w[5], xr[p0 + 12], a);
            a = fmaf(w[6], xr[p0 + 20], a);
            a = fmaf(w[7], xr[p0 + 21], a);
            a = fmaf(w[8], xr[p0 + 22], a);
            acc[k] = a;
        }
    }
    float bias = bb[oc];
    #pragma unroll
    for (int k = 0; k < 16; ++k) {
        float v = acc[k] + bias;
        v = v > 0.f ? v : 0.f;
        hs[oc * 64 + hg * 16 + k] = v;
    }
    __syncthreads();
    if (t < 64) {
        float n2 = 0.f;
        for (int c = 0; c < 64; ++c) { float v = hs[c * 64 + t]; n2 = fmaf(v, v, n2); }
        scl[t] = (n2 / (1.f + n2)) * rsqrtf(n2 + 1e-8f);
    }
    __syncthreads();
    #pragma unroll
    for (int k = 0; k < 4; ++k) {
        int idx4 = t + k * 256;
        int e0 = idx4 * 4;
        int hw0 = e0 & 63;
        float4 o;
        o.x = hs[e0 + 0] * scl[hw0 + 0];
        o.y = hs[e0 + 1] * scl[hw0 + 1];
        o.z = hs[e0 + 2] * scl[hw0 + 2];
        o.w = hs[e0 + 3] * scl[hw0 + 3];
        *(float4*)&h[(size_t)b * 4096 + e0] = o;
    }
}

// WT[o][c][d] = W[o*64+d][c]. One block per o.
__global__ __launch_bounds__(256) void transpose_w_kernel(
    const float* __restrict__ W, float* __restrict__ WT)
{
    __shared__ float tile[64][68];
    const int o = blockIdx.x;
    const int t = threadIdx.x;
    const int Q = t & 15, R = t >> 4;
    #pragma unroll
    for (int p = 0; p < 4; ++p) {
        int d = R + 16 * p;
        float4 v = *(const float4*)&W[((size_t)o * 64 + d) * 64 + 4 * Q];
        tile[d][4 * Q + 0] = v.x; tile[d][4 * Q + 1] = v.y;
        tile[d][4 * Q + 2] = v.z; tile[d][4 * Q + 3] = v.w;
    }
    __syncthreads();
    #pragma unroll
    for (int p = 0; p < 4; ++p) {
        int c = R + 16 * p;
        float4 v;
        v.x = tile[4 * Q + 0][c];
        v.y = tile[4 * Q + 1][c];
        v.z = tile[4 * Q + 2][c];
        v.w = tile[4 * Q + 3][c];
        *(float4*)&WT[((size_t)o * 64 + c) * 64 + 4 * Q] = v;
    }
}

__global__ __launch_bounds__(1024, 4) __attribute__((amdgpu_waves_per_eu(4, 4)))
void caps_fused(
    const float* __restrict__ h0,
    const float* __restrict__ W1, const float* __restrict__ WT1,
    const float* __restrict__ b1,
    const float* __restrict__ W2, const float* __restrict__ WT2,
    const float* __restrict__ b2,
    const float* __restrict__ b_basic, const float* __restrict__ b_cls,
    float* __restrict__ xbuf,   // [15][256][64]  den partials
    float* __restrict__ vbuf,   // [3][256][2048] layer-end v halves
    int*   __restrict__ flags,  // [256]
    float* __restrict__ out)
{
    __shared__ float HT[4096];        // h as [i][c], stride 64          16 KB
    __shared__ float HC[64 * 68];     // h as [c][i], stride 68          17 KB
    __shared__ float CC[2048];        // per-o_local comm rows (32x64)    8 KB
    __shared__ float PP[10240];       // partials [2][1024] + pad        40 KB
                                      // total 82944 B -> 1 block/CU

    const int B    = blockIdx.x;      // 0..255
    const int b    = B & 127;         // sample
    const int half = B >> 7;          // which o-half
    const int Pn   = B ^ 128;         // partner block (same XCD mod 8)
    const int t    = threadIdx.x;
    const int wv   = t >> 6;          // wave 0..15
    const int lane = t & 63;
    const int Q    = lane & 15;
    const int G    = lane >> 4;
    int step = 1;

    // build both h layouts from h0[b][c][i]
    {
        float4 v = *(const float4*)&h0[(size_t)b * 4096 + t * 4];
        int c  = t >> 4;
        int i0 = (t & 15) * 4;
        *(float4*)&HC[c * 68 + i0] = v;
        HT[(i0 + 0) * 64 + c] = v.x;
        HT[(i0 + 1) * 64 + c] = v.y;
        HT[(i0 + 2) * 64 + c] = v.z;
        HT[(i0 + 3) * 64 + c] = v.w;
    }

    auto layer = [&](auto finc, const float* __restrict__ Wmy,
                     const float* __restrict__ WTmy,
                     const float* __restrict__ biasmy,
                     const float* __restrict__ bsrcmy, int lidx) {
        constexpr bool FIN = decltype(finc)::value;
        constexpr int  NOO = FIN ? 1 : 2;      // o's per wave (local)
        const bool act = !FIN || wv < 5;       // FIN: 5 o's per half

        float bl[NOO];
        const float* pS[NOO];
        float4 bias4r[NOO];
        const ptrdiff_t dWU = Wmy - WTmy;
        if (act) {
            #pragma unroll
            for (int r = 0; r < NOO; ++r) {
                int ol = FIN ? wv : (wv + 16 * r);
                bl[r] = bsrcmy[ol * 64 + lane];
                pS[r] = WTmy + ol * 4096 + G * 64 + 4 * Q;
                bias4r[r] = *(const float4*)&biasmy[ol * 64 + 4 * Q];
            }
        }

        for (int it = 0; it < 3; ++it) {
            // ---- softmax over o: block partial + paired-block exchange ----
            float cc_[NOO], sc[NOO];
            float part = 0.f;
            if (act) {
                #pragma unroll
                for (int r = 0; r < NOO; ++r) { cc_[r] = expf(bl[r]); part += cc_[r]; }
            }
            PP[(it & 1) * 1024 + t] = part;
            __syncthreads();
            float bp = 0.f;
            #pragma unroll
            for (int w2 = 0; w2 < 16; ++w2)
                bp += PP[(it & 1) * 1024 + w2 * 64 + lane];
            {
                float* xs_me = xbuf + ((size_t)(step - 1) * 256 + B) * 64;
                const float* xs_pr = xbuf + ((size_t)(step - 1) * 256 + Pn) * 64;
                if (wv == 0) xs_me[lane] = bp;
                if (t == 0) {
                    __threadfence();     // drain wv0's store (same wave)
                    __hip_atomic_store(&flags[B], step, __ATOMIC_RELEASE,
                                       __HIP_MEMORY_SCOPE_AGENT);
                    while (__hip_atomic_load(&flags[Pn], __ATOMIC_ACQUIRE,
                                             __HIP_MEMORY_SCOPE_AGENT) < step) {}
                }
                __syncthreads();
                __threadfence();
                bp += xs_pr[lane];       // full denominator
            }
            float rden = 1.f / bp;
            ++step;
            if (act) {
                #pragma unroll
                for (int r = 0; r < NOO; ++r) {
                    int ol = FIN ? wv : (wv + 16 * r);
                    float cv = cc_[r] * rden;
                    CC[ol * 64 + lane] = cv;         // c row (own wave only)
                    #pragma unroll
                    for (int m = 1; m < 64; m <<= 1) cv += __shfl_xor(cv, m, 64);
                    sc[r] = cv;                      // sum_i c[o,i]
                }
            }
            __builtin_amdgcn_wave_barrier();

            if (act) {
                // ---- Y: y[o,4Q+j] = sum_i c[o,i] h[4Q+j,i] ----
                float4 yy[NOO];
                #pragma unroll
                for (int r = 0; r < NOO; ++r) yy[r] = make_float4(0.f, 0.f, 0.f, 0.f);
                #pragma unroll 4
                for (int k = 0; k < 16; ++k) {
                    int i = G * 16 + k;
                    float4 h4 = *(const float4*)&HT[i * 64 + 4 * Q];
                    #pragma unroll
                    for (int r = 0; r < NOO; ++r) {
                        int ol = FIN ? wv : (wv + 16 * r);
                        float cb = CC[ol * 64 + i];
                        yy[r].x = fmaf(cb, h4.x, yy[r].x);
                        yy[r].y = fmaf(cb, h4.y, yy[r].y);
                        yy[r].z = fmaf(cb, h4.z, yy[r].z);
                        yy[r].w = fmaf(cb, h4.w, yy[r].w);
                    }
                }
                #pragma unroll
                for (int m = 16; m <= 32; m <<= 1) {
                    #pragma unroll
                    for (int r = 0; r < NOO; ++r) {
                        yy[r].x += __shfl_xor(yy[r].x, m, 64);
                        yy[r].y += __shfl_xor(yy[r].y, m, 64);
                        yy[r].z += __shfl_xor(yy[r].z, m, 64);
                        yy[r].w += __shfl_xor(yy[r].w, m, 64);
                    }
                }
                if (G == 0) {
                    #pragma unroll
                    for (int r = 0; r < NOO; ++r)
                        *(float4*)&CC[(FIN ? wv : (wv + 16 * r)) * 64 + 4 * Q] = yy[r];
                }
                __builtin_amdgcn_wave_barrier();

                // ---- S: s[o,4Q+j] = sum_c WT[o][c][4Q+j] y[c] ----
                float4 s4[NOO];
                #pragma unroll
                for (int r = 0; r < NOO; ++r) s4[r] = make_float4(0.f, 0.f, 0.f, 0.f);
                #pragma unroll 8
                for (int k = 0; k < 16; ++k) {
                    #pragma unroll
                    for (int r = 0; r < NOO; ++r) {
                        int ol = FIN ? wv : (wv + 16 * r);
                        float4 w4 = *(const float4*)&pS[r][k << 8];
                        float yv  = CC[ol * 64 + 4 * k + G];
                        s4[r].x = fmaf(w4.x, yv, s4[r].x);
                        s4[r].y = fmaf(w4.y, yv, s4[r].y);
                        s4[r].z = fmaf(w4.z, yv, s4[r].z);
                        s4[r].w = fmaf(w4.w, yv, s4[r].w);
                    }
                }
                #pragma unroll
                for (int m = 16; m <= 32; m <<= 1) {
                    #pragma unroll
                    for (int r = 0; r < NOO; ++r) {
                        s4[r].x += __shfl_xor(s4[r].x, m, 64);
                        s4[r].y += __shfl_xor(s4[r].y, m, 64);
                        s4[r].z += __shfl_xor(s4[r].z, m, 64);
                        s4[r].w += __shfl_xor(s4[r].w, m, 64);
                    }
                }
                float vd[NOO];
                #pragma unroll
                for (int r = 0; r < NOO; ++r) {
                    int ol = FIN ? wv : (wv + 16 * r);
                    s4[r].x = fmaf(bias4r[r].x, sc[r], s4[r].x);
                    s4[r].y = fmaf(bias4r[r].y, sc[r], s4[r].y);
                    s4[r].z = fmaf(bias4r[r].z, sc[r], s4[r].z);
                    s4[r].w = fmaf(bias4r[r].w, sc[r], s4[r].w);
                    float n2 = s4[r].x * s4[r].x + s4[r].y * s4[r].y
                             + s4[r].z * s4[r].z + s4[r].w * s4[r].w;
                    #pragma unroll
                    for (int m = 1; m <= 8; m <<= 1) n2 += __shfl_xor(n2, m, 64);
                    float scale = (n2 / (1.f + n2)) * rsqrtf(n2 + 1e-8f);
                    float4 v4;
                    v4.x = s4[r].x * scale; v4.y = s4[r].y * scale;
                    v4.z = s4[r].z * scale; v4.w = s4[r].w * scale;
                    if (it < 2) {
                        float d = v4.x * bias4r[r].x + v4.y * bias4r[r].y
                                + v4.z * bias4r[r].z + v4.w * bias4r[r].w;
                        #pragma unroll
                        for (int m = 1; m <= 8; m <<= 1) d += __shfl_xor(d, m, 64);
                        vd[r] = d;                    // v . bias_o
                    }
                    if (G == 0) {
                        *(float4*)&CC[ol * 64 + 4 * Q] = v4;   // v row (persists)
                        if (FIN && it == 2) {
                            int og = half * 5 + wv;
                            *(float4*)&out[(size_t)b * 640 + og * 64 + 4 * Q] = v4;
                        }
                    }
                }

                if (it < 2) {
                    __builtin_amdgcn_wave_barrier();
                    // ---- U: u[o,4Q+j] = sum_d v[o,d] W[o*64+d][4Q+j] ----
                    float4 u4[NOO];
                    #pragma unroll
                    for (int r = 0; r < NOO; ++r) u4[r] = make_float4(0.f, 0.f, 0.f, 0.f);
                    #pragma unroll 8
                    for (int k = 0; k < 16; ++k) {
                        #pragma unroll
                        for (int r = 0; r < NOO; ++r) {
                            int ol = FIN ? wv : (wv + 16 * r);
                            float4 w4 = *(const float4*)&pS[r][(k << 8) + dWU];
                            float vv  = CC[ol * 64 + 4 * k + G];
                            u4[r].x = fmaf(vv, w4.x, u4[r].x);
                            u4[r].y = fmaf(vv, w4.y, u4[r].y);
                            u4[r].z = fmaf(vv, w4.z, u4[r].z);
                            u4[r].w = fmaf(vv, w4.w, u4[r].w);
                        }
                    }
                    #pragma unroll
                    for (int m = 16; m <= 32; m <<= 1) {
                        #pragma unroll
                        for (int r = 0; r < NOO; ++r) {
                            u4[r].x += __shfl_xor(u4[r].x, m, 64);
                            u4[r].y += __shfl_xor(u4[r].y, m, 64);
                            u4[r].z += __shfl_xor(u4[r].z, m, 64);
                            u4[r].w += __shfl_xor(u4[r].w, m, 64);
                        }
                    }
                    if (G == 0) {
                        #pragma unroll
                        for (int r = 0; r < NOO; ++r)
                            *(float4*)&CC[(FIN ? wv : (wv + 16 * r)) * 64 + 4 * Q] = u4[r];
                    }
                    __builtin_amdgcn_wave_barrier();

                    // ---- DB: db[o,4Q+j] = sum_c u[o,c] h[c,4Q+j] ----
                    float4 d4[NOO];
                    #pragma unroll
                    for (int r = 0; r < NOO; ++r) d4[r] = make_float4(0.f, 0.f, 0.f, 0.f);
                    #pragma unroll 4
                    for (int k = 0; k < 16; ++k) {
                        int c = G * 16 + k;
                        float4 hc4 = *(const float4*)&HC[c * 68 + 4 * Q];
                        #pragma unroll
                        for (int r = 0; r < NOO; ++r) {
                            int ol = FIN ? wv : (wv + 16 * r);
                            float ub = CC[ol * 64 + c];
                            d4[r].x = fmaf(ub, hc4.x, d4[r].x);
                            d4[r].y = fmaf(ub, hc4.y, d4[r].y);
                            d4[r].z = fmaf(ub, hc4.z, d4[r].z);
                            d4[r].w = fmaf(ub, hc4.w, d4[r].w);
                        }
                    }
                    #pragma unroll
                    for (int m = 16; m <= 32; m <<= 1) {
                        #pragma unroll
                        for (int r = 0; r < NOO; ++r) {
                            d4[r].x += __shfl_xor(d4[r].x, m, 64);
                            d4[r].y += __shfl_xor(d4[r].y, m, 64);
                            d4[r].z += __shfl_xor(d4[r].z, m, 64);
                            d4[r].w += __shfl_xor(d4[r].w, m, 64);
                        }
                    }
                    if (G == 0) {
                        #pragma unroll
                        for (int r = 0; r < NOO; ++r)
                            *(float4*)&CC[(FIN ? wv : (wv + 16 * r)) * 64 + 4 * Q] = d4[r];
                    }
                    __builtin_amdgcn_wave_barrier();
                    #pragma unroll
                    for (int r = 0; r < NOO; ++r)
                        bl[r] += CC[(FIN ? wv : (wv + 16 * r)) * 64 + lane] + vd[r];
                }
            }
        }

        // ---- layer end: exchange v halves, build next HT/HC ----
        __syncthreads();                 // CC v-rows final block-wide
        if (!FIN) {
            float* vb_me = vbuf + ((size_t)lidx * 256 + B) * 2048;
            const float* vb_pr = vbuf + ((size_t)lidx * 256 + Pn) * 2048;
            if (t < 512)
                *(float4*)&vb_me[t * 4] = *(const float4*)&CC[t * 4];
            __threadfence();             // each writer drains its own stores
            __syncthreads();             // all 512 writers done
            if (t == 0) {
                __hip_atomic_store(&flags[B], step, __ATOMIC_RELEASE,
                                   __HIP_MEMORY_SCOPE_AGENT);
                while (__hip_atomic_load(&flags[Pn], __ATOMIC_ACQUIRE,
                                         __HIP_MEMORY_SCOPE_AGENT) < step) {}
            }
            __syncthreads();
            __threadfence();
            if (t < 512) {               // my half from CC
                float4 vv = *(const float4*)&CC[t * 4];
                int ol = t >> 4, d0 = (t & 15) * 4;
                int og = half * 32 + ol;
                *(float4*)&HT[og * 64 + d0] = vv;
                HC[(d0 + 0) * 68 + og] = vv.x;
                HC[(d0 + 1) * 68 + og] = vv.y;
                HC[(d0 + 2) * 68 + og] = vv.z;
                HC[(d0 + 3) * 68 + og] = vv.w;
            } else {                     // partner half from vbuf
                int idx = t - 512;
                float4 pv = *(const float4*)&vb_pr[idx * 4];
                int ol = idx >> 4, d0 = (idx & 15) * 4;
                int og = (half ^ 1) * 32 + ol;
                *(float4*)&HT[og * 64 + d0] = pv;
                HC[(d0 + 0) * 68 + og] = pv.x;
                HC[(d0 + 1) * 68 + og] = pv.y;
                HC[(d0 + 2) * 68 + og] = pv.z;
                HC[(d0 + 3) * 68 + og] = pv.w;
            }
            ++step;
            // visibility of HT/HC for next layer: its den __syncthreads
        }
    };

    layer(std::integral_constant<bool, false>{},
          W1 + half * 32 * 4096, WT1 + half * 32 * 4096, b1 + half * 32 * 64,
          b_basic + (((size_t)0 * 128 + b) << 12) + half * 2048, 0);
    layer(std::integral_constant<bool, false>{},
          W1 + half * 32 * 4096, WT1 + half * 32 * 4096, b1 + half * 32 * 64,
          b_basic + (((size_t)1 * 128 + b) << 12) + half * 2048, 1);
    layer(std::integral_constant<bool, false>{},
          W1 + half * 32 * 4096, WT1 + half * 32 * 4096, b1 + half * 32 * 64,
          b_basic + (((size_t)2 * 128 + b) << 12) + half * 2048, 2);
    layer(std::integral_constant<bool, true>{},
          W2 + half * 5 * 4096, WT2 + half * 5 * 4096, b2 + half * 5 * 64,
          b_cls + (size_t)b * 640 + half * 5 * 64, 3);
}

extern "C" void kernel_launch(void* const* d_in, const int* in_sizes, int n_in,
                              void* d_out, int out_size, void* d_ws, size_t ws_size,
                              hipStream_t stream) {
    const float* x       = (const float*)d_in[0];
    const float* Wb      = (const float*)d_in[1];
    const float* bb      = (const float*)d_in[2];
    const float* W1      = (const float*)d_in[3];
    const float* b1      = (const float*)d_in[4];
    const float* W2      = (const float*)d_in[5];
    const float* b2      = (const float*)d_in[6];
    const float* b_basic = (const float*)d_in[7];
    const float* b_cls   = (const float*)d_in[8];
    float* out = (float*)d_out;

    float* h0    = (float*)d_ws;            // [128,64,64]        2 MB
    float* WT1   = h0 + 128 * 4096;         // [64,64,64]         1 MB
    float* WT2   = WT1 + 64 * 4096;         // [10,64,64]         160 KB
    float* xbuf  = WT2 + 10 * 4096;         // [15][256][64]      960 KB
    float* vbuf  = xbuf + 15 * 256 * 64;    // [3][256][2048]     6 MB
    int*   flags = (int*)(vbuf + 3 * 256 * 2048);   // [256]

    zero_flags_kernel<<<1, 256, 0, stream>>>(flags);
    transpose_w_kernel<<<64, 256, 0, stream>>>(W1, WT1);
    transpose_w_kernel<<<10, 256, 0, stream>>>(W2, WT2);
    conv_squash_kernel<<<128, 256, 0, stream>>>(x, Wb, bb, h0);
    caps_fused<<<256, 1024, 0, stream>>>(h0, W1, WT1, b1, W2, WT2, b2,
                                         b_basic, b_cls, xbuf, vbuf, flags, out);
}

// Round 9
// 179.499 us; speedup vs baseline: 7.6224x; 7.6224x over previous
//
#include <hip/hip_runtime.h>
#include <math.h>
#include <type_traits>

// ---------------------------------------------------------------------------
// CapsNet forward, fused routing with o-SPLIT across paired blocks:
//   256 blocks = 2 per sample (half the out-caps each) -> all 256 CUs busy.
//   Cross-block exchange (softmax denominator 64 f/iter; layer-end v 8 KB x3)
//   uses RELAXED SYSTEM-scope atomics (sc0+sc1: bypass L1/L2, coherent at the
//   chip-level Infinity Cache) + per-wave `s_waitcnt vmcnt(0)` ordering.
//   NO fences / NO acquire-release -> no L2 writeback/invalidate, W stays
//   L2-resident (round-8 lesson: agent fences flush the non-coherent L2s).
//   LDS > 80 KB forces 1 block/CU so all 256 blocks co-reside (proven r8).
// ---------------------------------------------------------------------------

#define SYS_ST(p, v) __hip_atomic_store((p), (v), __ATOMIC_RELAXED, __HIP_MEMORY_SCOPE_SYSTEM)
#define SYS_LD(p)    __hip_atomic_load((p), __ATOMIC_RELAXED, __HIP_MEMORY_SCOPE_SYSTEM)

__global__ void zero_flags_kernel(int* flags) { flags[threadIdx.x] = 0; }

__global__ __launch_bounds__(256) void conv_squash_kernel(
    const float* __restrict__ x,   // [128,64,8,8]
    const float* __restrict__ Wb,  // [64,64,3,3]
    const float* __restrict__ bb,  // [64]
    float* __restrict__ h)         // [128,64,64]
{
    __shared__ float xs[6400];
    __shared__ float hs[4096];
    __shared__ float scl[64];
    const int b = blockIdx.x;
    const int t = threadIdx.x;

    for (int idx = t; idx < 6400; idx += 256) xs[idx] = 0.f;
    __syncthreads();
    #pragma unroll
    for (int k = 0; k < 4; ++k) {
        int idx4 = t + k * 256;
        float4 v = *(const float4*)&x[(size_t)b * 4096 + idx4 * 4];
        int e0 = idx4 * 4;
        int c  = e0 >> 6;
        int hw = e0 & 63;
        int r = hw >> 3, cc = hw & 7;
        float* xp = &xs[c * 100 + (r + 1) * 10 + (cc + 1)];
        xp[0] = v.x; xp[1] = v.y; xp[2] = v.z; xp[3] = v.w;
    }
    __syncthreads();

    const int oc = t >> 2;
    const int hg = t & 3;
    float acc[16];
    #pragma unroll
    for (int k = 0; k < 16; ++k) acc[k] = 0.f;

    const float* wp = Wb + (size_t)oc * 64 * 9;
    for (int ic = 0; ic < 64; ++ic) {
        float w[9];
        #pragma unroll
        for (int j = 0; j < 9; ++j) w[j] = wp[ic * 9 + j];
        const float* xr = &xs[ic * 100];
        #pragma unroll
        for (int k = 0; k < 16; ++k) {
            int hw = hg * 16 + k;
            int r = hw >> 3, cc = hw & 7;
            int p0 = r * 10 + cc;
            float a = acc[k];
            a = fmaf(w[0], xr[p0],      a);
            a = fmaf(w[1], xr[p0 + 1],  a);
            a = fmaf(w[2], xr[p0 + 2],  a);
            a = fmaf(w[3], xr[p0 + 10], a);
            a = fmaf(w[4], xr[p0 + 11], a);
            a = fmaf(w[5], xr[p0 + 12], a);
            a = fmaf(w[6], xr[p0 + 20], a);
            a = fmaf(w[7], xr[p0 + 21], a);
            a = fmaf(w[8], xr[p0 + 22], a);
            acc[k] = a;
        }
    }
    float bias = bb[oc];
    #pragma unroll
    for (int k = 0; k < 16; ++k) {
        float v = acc[k] + bias;
        v = v > 0.f ? v : 0.f;
        hs[oc * 64 + hg * 16 + k] = v;
    }
    __syncthreads();
    if (t < 64) {
        float n2 = 0.f;
        for (int c = 0; c < 64; ++c) { float v = hs[c * 64 + t]; n2 = fmaf(v, v, n2); }
        scl[t] = (n2 / (1.f + n2)) * rsqrtf(n2 + 1e-8f);
    }
    __syncthreads();
    #pragma unroll
    for (int k = 0; k < 4; ++k) {
        int idx4 = t + k * 256;
        int e0 = idx4 * 4;
        int hw0 = e0 & 63;
        float4 o;
        o.x = hs[e0 + 0] * scl[hw0 + 0];
        o.y = hs[e0 + 1] * scl[hw0 + 1];
        o.z = hs[e0 + 2] * scl[hw0 + 2];
        o.w = hs[e0 + 3] * scl[hw0 + 3];
        *(float4*)&h[(size_t)b * 4096 + e0] = o;
    }
}

// WT[o][c][d] = W[o*64+d][c]. One block per o.
__global__ __launch_bounds__(256) void transpose_w_kernel(
    const float* __restrict__ W, float* __restrict__ WT)
{
    __shared__ float tile[64][68];
    const int o = blockIdx.x;
    const int t = threadIdx.x;
    const int Q = t & 15, R = t >> 4;
    #pragma unroll
    for (int p = 0; p < 4; ++p) {
        int d = R + 16 * p;
        float4 v = *(const float4*)&W[((size_t)o * 64 + d) * 64 + 4 * Q];
        tile[d][4 * Q + 0] = v.x; tile[d][4 * Q + 1] = v.y;
        tile[d][4 * Q + 2] = v.z; tile[d][4 * Q + 3] = v.w;
    }
    __syncthreads();
    #pragma unroll
    for (int p = 0; p < 4; ++p) {
        int c = R + 16 * p;
        float4 v;
        v.x = tile[4 * Q + 0][c];
        v.y = tile[4 * Q + 1][c];
        v.z = tile[4 * Q + 2][c];
        v.w = tile[4 * Q + 3][c];
        *(float4*)&WT[((size_t)o * 64 + c) * 64 + 4 * Q] = v;
    }
}

__global__ __launch_bounds__(1024, 4) __attribute__((amdgpu_waves_per_eu(4, 4)))
void caps_fused(
    const float* __restrict__ h0,
    const float* __restrict__ W1, const float* __restrict__ WT1,
    const float* __restrict__ b1,
    const float* __restrict__ W2, const float* __restrict__ WT2,
    const float* __restrict__ b2,
    const float* __restrict__ b_basic, const float* __restrict__ b_cls,
    float* __restrict__ xbuf,   // [15][256][64]  den partials
    float* __restrict__ vbuf,   // [3][256][2048] layer-end v halves
    int*   __restrict__ flags,  // [256*16] (64B stride per block)
    float* __restrict__ out)
{
    __shared__ float HT[4096];        // h as [i][c], stride 64          16 KB
    __shared__ float HC[64 * 68];     // h as [c][i], stride 68          17 KB
    __shared__ float CC[2048];        // per-o_local comm rows (32x64)    8 KB
    __shared__ float PP[10240];       // partials [2][1024] + pad        40 KB
                                      // total 82944 B -> 1 block/CU

    const int B    = blockIdx.x;      // 0..255
    const int b    = B & 127;         // sample
    const int half = B >> 7;          // which o-half
    const int Pn   = B ^ 128;         // partner block
    const int t    = threadIdx.x;
    const int wv   = t >> 6;          // wave 0..15
    const int lane = t & 63;
    const int Q    = lane & 15;
    const int G    = lane >> 4;
    int step = 1;

    // build both h layouts from h0[b][c][i]
    {
        float4 v = *(const float4*)&h0[(size_t)b * 4096 + t * 4];
        int c  = t >> 4;
        int i0 = (t & 15) * 4;
        *(float4*)&HC[c * 68 + i0] = v;
        HT[(i0 + 0) * 64 + c] = v.x;
        HT[(i0 + 1) * 64 + c] = v.y;
        HT[(i0 + 2) * 64 + c] = v.z;
        HT[(i0 + 3) * 64 + c] = v.w;
    }

    auto layer = [&](auto finc, const float* __restrict__ Wmy,
                     const float* __restrict__ WTmy,
                     const float* __restrict__ biasmy,
                     const float* __restrict__ bsrcmy, int lidx) {
        constexpr bool FIN = decltype(finc)::value;
        constexpr int  NOO = FIN ? 1 : 2;      // o's per wave (local)
        const bool act = !FIN || wv < 5;       // FIN: 5 o's per half

        float bl[NOO];
        const float* pS[NOO];
        float4 bias4r[NOO];
        const ptrdiff_t dWU = Wmy - WTmy;
        if (act) {
            #pragma unroll
            for (int r = 0; r < NOO; ++r) {
                int ol = FIN ? wv : (wv + 16 * r);
                bl[r] = bsrcmy[ol * 64 + lane];
                pS[r] = WTmy + ol * 4096 + G * 64 + 4 * Q;
                bias4r[r] = *(const float4*)&biasmy[ol * 64 + 4 * Q];
            }
        }

        for (int it = 0; it < 3; ++it) {
            // ---- softmax over o: block partial + fence-free L3 exchange ----
            float cc_[NOO], sc[NOO];
            float part = 0.f;
            if (act) {
                #pragma unroll
                for (int r = 0; r < NOO; ++r) { cc_[r] = expf(bl[r]); part += cc_[r]; }
            }
            PP[(it & 1) * 1024 + t] = part;
            __syncthreads();
            float bp = 0.f;
            #pragma unroll
            for (int w2 = 0; w2 < 16; ++w2)
                bp += PP[(it & 1) * 1024 + w2 * 64 + lane];
            {
                float* xs_me = xbuf + ((size_t)(step - 1) * 256 + B) * 64;
                const float* xs_pr = xbuf + ((size_t)(step - 1) * 256 + Pn) * 64;
                if (wv == 0) {
                    SYS_ST(&xs_me[lane], bp);
                    asm volatile("s_waitcnt vmcnt(0)" ::: "memory");
                    if (t == 0) {
                        SYS_ST(&flags[B * 16], step);
                        while (SYS_LD(&flags[Pn * 16]) < step) {}
                    }
                }
                __syncthreads();
                asm volatile("" ::: "memory");
                bp += SYS_LD(&xs_pr[lane]);      // full denominator
            }
            float rden = 1.f / bp;
            ++step;
            if (act) {
                #pragma unroll
                for (int r = 0; r < NOO; ++r) {
                    int ol = FIN ? wv : (wv + 16 * r);
                    float cv = cc_[r] * rden;
                    CC[ol * 64 + lane] = cv;         // c row (own wave only)
                    #pragma unroll
                    for (int m = 1; m < 64; m <<= 1) cv += __shfl_xor(cv, m, 64);
                    sc[r] = cv;                      // sum_i c[o,i]
                }
            }
            __builtin_amdgcn_wave_barrier();

            if (act) {
                // ---- Y: y[o,4Q+j] = sum_i c[o,i] h[4Q+j,i] ----
                float4 yy[NOO];
                #pragma unroll
                for (int r = 0; r < NOO; ++r) yy[r] = make_float4(0.f, 0.f, 0.f, 0.f);
                #pragma unroll 4
                for (int k = 0; k < 16; ++k) {
                    int i = G * 16 + k;
                    float4 h4 = *(const float4*)&HT[i * 64 + 4 * Q];
                    #pragma unroll
                    for (int r = 0; r < NOO; ++r) {
                        int ol = FIN ? wv : (wv + 16 * r);
                        float cb = CC[ol * 64 + i];
                        yy[r].x = fmaf(cb, h4.x, yy[r].x);
                        yy[r].y = fmaf(cb, h4.y, yy[r].y);
                        yy[r].z = fmaf(cb, h4.z, yy[r].z);
                        yy[r].w = fmaf(cb, h4.w, yy[r].w);
                    }
                }
                #pragma unroll
                for (int m = 16; m <= 32; m <<= 1) {
                    #pragma unroll
                    for (int r = 0; r < NOO; ++r) {
                        yy[r].x += __shfl_xor(yy[r].x, m, 64);
                        yy[r].y += __shfl_xor(yy[r].y, m, 64);
                        yy[r].z += __shfl_xor(yy[r].z, m, 64);
                        yy[r].w += __shfl_xor(yy[r].w, m, 64);
                    }
                }
                if (G == 0) {
                    #pragma unroll
                    for (int r = 0; r < NOO; ++r)
                        *(float4*)&CC[(FIN ? wv : (wv + 16 * r)) * 64 + 4 * Q] = yy[r];
                }
                __builtin_amdgcn_wave_barrier();

                // ---- S: s[o,4Q+j] = sum_c WT[o][c][4Q+j] y[c] ----
                float4 s4[NOO];
                #pragma unroll
                for (int r = 0; r < NOO; ++r) s4[r] = make_float4(0.f, 0.f, 0.f, 0.f);
                #pragma unroll 8
                for (int k = 0; k < 16; ++k) {
                    #pragma unroll
                    for (int r = 0; r < NOO; ++r) {
                        int ol = FIN ? wv : (wv + 16 * r);
                        float4 w4 = *(const float4*)&pS[r][k << 8];
                        float yv  = CC[ol * 64 + 4 * k + G];
                        s4[r].x = fmaf(w4.x, yv, s4[r].x);
                        s4[r].y = fmaf(w4.y, yv, s4[r].y);
                        s4[r].z = fmaf(w4.z, yv, s4[r].z);
                        s4[r].w = fmaf(w4.w, yv, s4[r].w);
                    }
                }
                #pragma unroll
                for (int m = 16; m <= 32; m <<= 1) {
                    #pragma unroll
                    for (int r = 0; r < NOO; ++r) {
                        s4[r].x += __shfl_xor(s4[r].x, m, 64);
                        s4[r].y += __shfl_xor(s4[r].y, m, 64);
                        s4[r].z += __shfl_xor(s4[r].z, m, 64);
                        s4[r].w += __shfl_xor(s4[r].w, m, 64);
                    }
                }
                float vd[NOO];
                #pragma unroll
                for (int r = 0; r < NOO; ++r) {
                    int ol = FIN ? wv : (wv + 16 * r);
                    s4[r].x = fmaf(bias4r[r].x, sc[r], s4[r].x);
                    s4[r].y = fmaf(bias4r[r].y, sc[r], s4[r].y);
                    s4[r].z = fmaf(bias4r[r].z, sc[r], s4[r].z);
                    s4[r].w = fmaf(bias4r[r].w, sc[r], s4[r].w);
                    float n2 = s4[r].x * s4[r].x + s4[r].y * s4[r].y
                             + s4[r].z * s4[r].z + s4[r].w * s4[r].w;
                    #pragma unroll
                    for (int m = 1; m <= 8; m <<= 1) n2 += __shfl_xor(n2, m, 64);
                    float scale = (n2 / (1.f + n2)) * rsqrtf(n2 + 1e-8f);
                    float4 v4;
                    v4.x = s4[r].x * scale; v4.y = s4[r].y * scale;
                    v4.z = s4[r].z * scale; v4.w = s4[r].w * scale;
                    if (it < 2) {
                        float d = v4.x * bias4r[r].x + v4.y * bias4r[r].y
                                + v4.z * bias4r[r].z + v4.w * bias4r[r].w;
                        #pragma unroll
                        for (int m = 1; m <= 8; m <<= 1) d += __shfl_xor(d, m, 64);
                        vd[r] = d;                    // v . bias_o
                    }
                    if (G == 0) {
                        *(float4*)&CC[ol * 64 + 4 * Q] = v4;   // v row (persists)
                        if (FIN && it == 2) {
                            int og = half * 5 + wv;
                            *(float4*)&out[(size_t)b * 640 + og * 64 + 4 * Q] = v4;
                        }
                    }
                }

                if (it < 2) {
                    __builtin_amdgcn_wave_barrier();
                    // ---- U: u[o,4Q+j] = sum_d v[o,d] W[o*64+d][4Q+j] ----
                    float4 u4[NOO];
                    #pragma unroll
                    for (int r = 0; r < NOO; ++r) u4[r] = make_float4(0.f, 0.f, 0.f, 0.f);
                    #pragma unroll 8
                    for (int k = 0; k < 16; ++k) {
                        #pragma unroll
                        for (int r = 0; r < NOO; ++r) {
                            int ol = FIN ? wv : (wv + 16 * r);
                            float4 w4 = *(const float4*)&pS[r][(k << 8) + dWU];
                            float vv  = CC[ol * 64 + 4 * k + G];
                            u4[r].x = fmaf(vv, w4.x, u4[r].x);
                            u4[r].y = fmaf(vv, w4.y, u4[r].y);
                            u4[r].z = fmaf(vv, w4.z, u4[r].z);
                            u4[r].w = fmaf(vv, w4.w, u4[r].w);
                        }
                    }
                    #pragma unroll
                    for (int m = 16; m <= 32; m <<= 1) {
                        #pragma unroll
                        for (int r = 0; r < NOO; ++r) {
                            u4[r].x += __shfl_xor(u4[r].x, m, 64);
                            u4[r].y += __shfl_xor(u4[r].y, m, 64);
                            u4[r].z += __shfl_xor(u4[r].z, m, 64);
                            u4[r].w += __shfl_xor(u4[r].w, m, 64);
                        }
                    }
                    if (G == 0) {
                        #pragma unroll
                        for (int r = 0; r < NOO; ++r)
                            *(float4*)&CC[(FIN ? wv : (wv + 16 * r)) * 64 + 4 * Q] = u4[r];
                    }
                    __builtin_amdgcn_wave_barrier();

                    // ---- DB: db[o,4Q+j] = sum_c u[o,c] h[c,4Q+j] ----
                    float4 d4[NOO];
                    #pragma unroll
                    for (int r = 0; r < NOO; ++r) d4[r] = make_float4(0.f, 0.f, 0.f, 0.f);
                    #pragma unroll 4
                    for (int k = 0; k < 16; ++k) {
                        int c = G * 16 + k;
                        float4 hc4 = *(const float4*)&HC[c * 68 + 4 * Q];
                        #pragma unroll
                        for (int r = 0; r < NOO; ++r) {
                            int ol = FIN ? wv : (wv + 16 * r);
                            float ub = CC[ol * 64 + c];
                            d4[r].x = fmaf(ub, hc4.x, d4[r].x);
                            d4[r].y = fmaf(ub, hc4.y, d4[r].y);
                            d4[r].z = fmaf(ub, hc4.z, d4[r].z);
                            d4[r].w = fmaf(ub, hc4.w, d4[r].w);
                        }
                    }
                    #pragma unroll
                    for (int m = 16; m <= 32; m <<= 1) {
                        #pragma unroll
                        for (int r = 0; r < NOO; ++r) {
                            d4[r].x += __shfl_xor(d4[r].x, m, 64);
                            d4[r].y += __shfl_xor(d4[r].y, m, 64);
                            d4[r].z += __shfl_xor(d4[r].z, m, 64);
                            d4[r].w += __shfl_xor(d4[r].w, m, 64);
                        }
                    }
                    if (G == 0) {
                        #pragma unroll
                        for (int r = 0; r < NOO; ++r)
                            *(float4*)&CC[(FIN ? wv : (wv + 16 * r)) * 64 + 4 * Q] = d4[r];
                    }
                    __builtin_amdgcn_wave_barrier();
                    #pragma unroll
                    for (int r = 0; r < NOO; ++r)
                        bl[r] += CC[(FIN ? wv : (wv + 16 * r)) * 64 + lane] + vd[r];
                }
            }
        }

        // ---- layer end: exchange v halves (fence-free L3), build HT/HC ----
        __syncthreads();                 // CC v-rows final block-wide
        if (!FIN) {
            float* vb_me = vbuf + ((size_t)lidx * 256 + B) * 2048;
            const float* vb_pr = vbuf + ((size_t)lidx * 256 + Pn) * 2048;
            if (t < 512) {
                float4 vv = *(const float4*)&CC[t * 4];
                SYS_ST(&vb_me[t * 4 + 0], vv.x);
                SYS_ST(&vb_me[t * 4 + 1], vv.y);
                SYS_ST(&vb_me[t * 4 + 2], vv.z);
                SYS_ST(&vb_me[t * 4 + 3], vv.w);
            }
            asm volatile("s_waitcnt vmcnt(0)" ::: "memory");  // each wave drains
            __syncthreads();             // all waves' stores complete
            if (t == 0) {
                SYS_ST(&flags[B * 16], step);
                while (SYS_LD(&flags[Pn * 16]) < step) {}
            }
            __syncthreads();
            asm volatile("" ::: "memory");
            if (t < 512) {               // my half from CC
                float4 vv = *(const float4*)&CC[t * 4];
                int ol = t >> 4, d0 = (t & 15) * 4;
                int og = half * 32 + ol;
                *(float4*)&HT[og * 64 + d0] = vv;
                HC[(d0 + 0) * 68 + og] = vv.x;
                HC[(d0 + 1) * 68 + og] = vv.y;
                HC[(d0 + 2) * 68 + og] = vv.z;
                HC[(d0 + 3) * 68 + og] = vv.w;
            } else {                     // partner half from vbuf (L3-fresh)
                int idx = t - 512;
                float4 pv;
                pv.x = SYS_LD(&vb_pr[idx * 4 + 0]);
                pv.y = SYS_LD(&vb_pr[idx * 4 + 1]);
                pv.z = SYS_LD(&vb_pr[idx * 4 + 2]);
                pv.w = SYS_LD(&vb_pr[idx * 4 + 3]);
                int ol = idx >> 4, d0 = (idx & 15) * 4;
                int og = (half ^ 1) * 32 + ol;
                *(float4*)&HT[og * 64 + d0] = pv;
                HC[(d0 + 0) * 68 + og] = pv.x;
                HC[(d0 + 1) * 68 + og] = pv.y;
                HC[(d0 + 2) * 68 + og] = pv.z;
                HC[(d0 + 3) * 68 + og] = pv.w;
            }
            ++step;
            // visibility of HT/HC for next layer: its den __syncthreads
        }
    };

    layer(std::integral_constant<bool, false>{},
          W1 + half * 32 * 4096, WT1 + half * 32 * 4096, b1 + half * 32 * 64,
          b_basic + (((size_t)0 * 128 + b) << 12) + half * 2048, 0);
    layer(std::integral_constant<bool, false>{},
          W1 + half * 32 * 4096, WT1 + half * 32 * 4096, b1 + half * 32 * 64,
          b_basic + (((size_t)1 * 128 + b) << 12) + half * 2048, 1);
    layer(std::integral_constant<bool, false>{},
          W1 + half * 32 * 4096, WT1 + half * 32 * 4096, b1 + half * 32 * 64,
          b_basic + (((size_t)2 * 128 + b) << 12) + half * 2048, 2);
    layer(std::integral_constant<bool, true>{},
          W2 + half * 5 * 4096, WT2 + half * 5 * 4096, b2 + half * 5 * 64,
          b_cls + (size_t)b * 640 + half * 5 * 64, 3);
}

extern "C" void kernel_launch(void* const* d_in, const int* in_sizes, int n_in,
                              void* d_out, int out_size, void* d_ws, size_t ws_size,
                              hipStream_t stream) {
    const float* x       = (const float*)d_in[0];
    const float* Wb      = (const float*)d_in[1];
    const float* bb      = (const float*)d_in[2];
    const float* W1      = (const float*)d_in[3];
    const float* b1      = (const float*)d_in[4];
    const float* W2      = (const float*)d_in[5];
    const float* b2      = (const float*)d_in[6];
    const float* b_basic = (const float*)d_in[7];
    const float* b_cls   = (const float*)d_in[8];
    float* out = (float*)d_out;

    float* h0    = (float*)d_ws;            // [128,64,64]        2 MB
    float* WT1   = h0 + 128 * 4096;         // [64,64,64]         1 MB
    float* WT2   = WT1 + 64 * 4096;         // [10,64,64]         160 KB
    float* xbuf  = WT2 + 10 * 4096;         // [15][256][64]      960 KB
    float* vbuf  = xbuf + 15 * 256 * 64;    // [3][256][2048]     6 MB
    int*   flags = (int*)(vbuf + 3 * 256 * 2048);   // [256*16]   16 KB

    zero_flags_kernel<<<4, 1024, 0, stream>>>(flags);
    transpose_w_kernel<<<64, 256, 0, stream>>>(W1, WT1);
    transpose_w_kernel<<<10, 256, 0, stream>>>(W2, WT2);
    conv_squash_kernel<<<128, 256, 0, stream>>>(x, Wb, bb, h0);
    caps_fused<<<256, 1024, 0, stream>>>(h0, W1, WT1, b1, W2, WT2, b2,
                                         b_basic, b_cls, xbuf, vbuf, flags, out);
}